// Round 2
// baseline (193.032 us; speedup 1.0000x reference)
//
#include <hip/hip_runtime.h>
#include <hip/hip_cooperative_groups.h>
#include <cmath>

namespace cg = cooperative_groups;

constexpr int B_ = 2, H_ = 8, N_ = 2048, DK_ = 64, DV_ = 64;
constexpr int BH_ = B_ * H_;      // 16
constexpr int C_ = 64;            // chunk size
constexpr int NC_ = N_ / C_;      // 32 chunks per (b,h)
constexpr int NCH_ = BH_ * NC_;   // 512 chunks total

// One block per chunk. Phases:
//  0: omask row-sums -> qc,kc (LDS only)          [dominant: 512 KB HBM/block]
//  1: stage kbar (row-major + transposed) and v in LDS; chunk-local sums
//  --- grid.sync ---
//  2: exclusive prefix scan over chunks (per bh) into pref buffers
//  --- grid.sync ---
//  3: S = qbar kbarT (causal), O = qbar*Dpre + S*V, P, write out.
__global__ __launch_bounds__(256, 2) void fused_kernel(
    const float* __restrict__ qg, const float* __restrict__ kg,
    const float* __restrict__ vg, const float* __restrict__ om,
    float* __restrict__ lksum, float* __restrict__ lkv,
    float* __restrict__ pksum, float* __restrict__ pkv,
    float* __restrict__ outg)
{
  __shared__ float kb[C_][DK_];     // phase1: kbar row-major; phase3: qbT[a][i]
  __shared__ float kbT[DK_][C_];    // kbarT[a][j]; phase3 reused as St[j][i]
  __shared__ float vs[C_][DV_];
  __shared__ float smqc[C_], smkc[C_];

  const int chunk = blockIdx.x;
  const int bh = chunk >> 5, ci = chunk & 31;
  const int r0 = ci * C_;
  const size_t gbase = (size_t)(bh * N_ + r0) * DK_;
  const int t = threadIdx.x;

  // Early-issue q/k/v chunk loads; latency hides under the omask stream.
  float4 kr[4], vr[4], qr[4];
#pragma unroll
  for (int p = 0; p < 4; ++p) {
    int f = t + p * 256;
    kr[p] = *(const float4*)(kg + gbase + (size_t)f * 4);
    vr[p] = *(const float4*)(vg + gbase + (size_t)f * 4);
    qr[p] = *(const float4*)(qg + gbase + (size_t)f * 4);
  }

  // ---- Phase 0: omask row sums (wave-per-row, 16 rows per wave) ----
  {
    const int w = t >> 6, lane = t & 63;
    const float* ob = om + (size_t)(bh * N_ + r0) * N_;
    for (int rr = 0; rr < 16; ++rr) {
      const int row = w * 16 + rr;
      const float* rp = ob + (size_t)row * N_;
      float s = 0.f;
#pragma unroll
      for (int kk = 0; kk < 8; ++kk) {
        float4 x = *(const float4*)(rp + kk * 256 + lane * 4);
        s += (x.x + x.y) + (x.z + x.w);
      }
#pragma unroll
      for (int off = 32; off; off >>= 1) s += __shfl_xor(s, off, 64);
      if (lane == 0) {
        float o0 = rp[0];
        smqc[row] = o0 / sqrtf(s);
        smkc[row] = 1.0f / o0;
      }
    }
  }
  __syncthreads();

  // ---- Phase 1: stage kbar/v, chunk-local sums ----
#pragma unroll
  for (int p = 0; p < 4; ++p) {
    int f = t + p * 256;
    int row = f >> 4, col = (f & 15) * 4;
    float sc = smkc[row];
    float4 k4 = kr[p];
    k4.x *= sc; k4.y *= sc; k4.z *= sc; k4.w *= sc;
    *(float4*)&kb[row][col] = k4;
    kbT[col + 0][row] = k4.x;     // transposed copy (rare conflicted writes, ok)
    kbT[col + 1][row] = k4.y;
    kbT[col + 2][row] = k4.z;
    kbT[col + 3][row] = k4.w;
    *(float4*)&vs[row][col] = vr[p];
  }
  __syncthreads();
  {
    int dk0 = (t & 15) * 4, dv0 = (t >> 4) * 4;
    float acc[4][4] = {};
    float ks[4] = {};
    for (int r = 0; r < C_; ++r) {
      float4 k4 = *(const float4*)&kb[r][dk0];
      float4 v4 = *(const float4*)&vs[r][dv0];
      float ka[4] = {k4.x, k4.y, k4.z, k4.w};
      float va[4] = {v4.x, v4.y, v4.z, v4.w};
#pragma unroll
      for (int i = 0; i < 4; ++i) {
        ks[i] += ka[i];
#pragma unroll
        for (int j = 0; j < 4; ++j) acc[i][j] += ka[i] * va[j];
      }
    }
    float* kvc = lkv + (size_t)chunk * (DK_ * DV_);
#pragma unroll
    for (int i = 0; i < 4; ++i)
      *(float4*)(kvc + (size_t)(dk0 + i) * DV_ + dv0) =
          make_float4(acc[i][0], acc[i][1], acc[i][2], acc[i][3]);
    if (t < 16) {
#pragma unroll
      for (int i = 0; i < 4; ++i) lksum[(size_t)chunk * DK_ + dk0 + i] = ks[i];
    }
  }

  cg::this_grid().sync();

  // ---- Phase 2: exclusive prefix scan over chunks per bh ----
  {
    constexpr int PER = DK_ * DV_ + DK_;   // 4160 per bh
    int g = blockIdx.x * 256 + t;
    if (g < BH_ * PER) {
      int sbh = g / PER, e = g - sbh * PER;
      float run = 0.f;
      if (e < DK_ * DV_) {
        const float* src = lkv + (size_t)sbh * NC_ * (DK_ * DV_) + e;
        float* dst = pkv + (size_t)sbh * NC_ * (DK_ * DV_) + e;
        for (int cc = 0; cc < NC_; ++cc) {
          dst[(size_t)cc * (DK_ * DV_)] = run;
          run += src[(size_t)cc * (DK_ * DV_)];
        }
      } else {
        int e2 = e - DK_ * DV_;
        const float* src = lksum + (size_t)sbh * NC_ * DK_ + e2;
        float* dst = pksum + (size_t)sbh * NC_ * DK_ + e2;
        for (int cc = 0; cc < NC_; ++cc) {
          dst[(size_t)cc * DK_] = run;
          run += src[(size_t)cc * DK_];
        }
      }
    }
  }

  cg::this_grid().sync();

  // ---- Phase 3: outputs ----
  float (*qbT)[C_] = (float(*)[C_])kb;   // reuse kb space
#pragma unroll
  for (int p = 0; p < 4; ++p) {
    int f = t + p * 256;
    int row = f >> 4, col = (f & 15) * 4;
    float sc = smqc[row];
    float4 q4 = qr[p];
    qbT[col + 0][row] = q4.x * sc;
    qbT[col + 1][row] = q4.y * sc;
    qbT[col + 2][row] = q4.z * sc;
    qbT[col + 3][row] = q4.w * sc;
  }
  __syncthreads();

  // Phase A: causal S tile, 4x4 per thread
  int i0 = (t & 15) * 4, j0 = (t >> 4) * 4;
  float acc[4][4] = {};
  for (int a = 0; a < DK_; ++a) {
    float4 q4 = *(const float4*)&qbT[a][i0];
    float4 k4 = *(const float4*)&kbT[a][j0];
    float qa[4] = {q4.x, q4.y, q4.z, q4.w};
    float kk[4] = {k4.x, k4.y, k4.z, k4.w};
#pragma unroll
    for (int ii = 0; ii < 4; ++ii)
#pragma unroll
      for (int jj = 0; jj < 4; ++jj) acc[ii][jj] += qa[ii] * kk[jj];
  }
  __syncthreads();                 // all reads of kbT done
  float (*St)[C_] = kbT;           // reuse kbT as transposed S
#pragma unroll
  for (int jj = 0; jj < 4; ++jj) {
    int j = j0 + jj;
    float4 w;
    w.x = (j <= i0 + 0) ? acc[0][jj] : 0.f;
    w.y = (j <= i0 + 1) ? acc[1][jj] : 0.f;
    w.z = (j <= i0 + 2) ? acc[2][jj] : 0.f;
    w.w = (j <= i0 + 3) ? acc[3][jj] : 0.f;
    *(float4*)&St[j][i0] = w;
  }
  __syncthreads();

  // Phase B: O = qb*Dpre + S*V ; P = qb*Tpre + rowsum(S)
  {
    int bi0 = (t >> 4) * 4, c0 = (t & 15) * 4;
    const float* kvp = pkv + (size_t)chunk * (DK_ * DV_);
    const float* tp = pksum + (size_t)chunk * DK_;
    float o[4][4] = {};
    float pp[4] = {};
    for (int a = 0; a < DK_; ++a) {
      float4 q4 = *(const float4*)&qbT[a][bi0];
      float4 d4 = *(const float4*)(kvp + (size_t)a * DV_ + c0);
      float tv = tp[a];
      float qa[4] = {q4.x, q4.y, q4.z, q4.w};
      float da[4] = {d4.x, d4.y, d4.z, d4.w};
#pragma unroll
      for (int ii = 0; ii < 4; ++ii) {
        pp[ii] += qa[ii] * tv;
#pragma unroll
        for (int cc = 0; cc < 4; ++cc) o[ii][cc] += qa[ii] * da[cc];
      }
    }
    for (int j = 0; j < C_; ++j) {
      float4 s4 = *(const float4*)&St[j][bi0];
      float4 v4 = *(const float4*)&vs[j][c0];
      float sa[4] = {s4.x, s4.y, s4.z, s4.w};
      float va[4] = {v4.x, v4.y, v4.z, v4.w};
#pragma unroll
      for (int ii = 0; ii < 4; ++ii) {
        pp[ii] += sa[ii];
#pragma unroll
        for (int cc = 0; cc < 4; ++cc) o[ii][cc] += sa[ii] * va[cc];
      }
    }
    float* obp = outg + (size_t)(bh * N_ + r0) * DV_;
#pragma unroll
    for (int ii = 0; ii < 4; ++ii) {
      float P = fmaxf(fabsf(pp[ii]), 1.0f);
      float inv = 1.0f / P;
      *(float4*)(obp + (size_t)(bi0 + ii) * DV_ + c0) =
          make_float4(o[ii][0] * inv, o[ii][1] * inv,
                      o[ii][2] * inv, o[ii][3] * inv);
    }
  }
}

// ---------------------------------------------------------------------------
extern "C" void kernel_launch(void* const* d_in, const int* in_sizes, int n_in,
                              void* d_out, int out_size, void* d_ws, size_t ws_size,
                              hipStream_t stream) {
  const float* q = (const float*)d_in[0];
  const float* k = (const float*)d_in[1];
  const float* v = (const float*)d_in[2];
  const float* om = (const float*)d_in[3];
  float* out = (float*)d_out;

  float* ws = (float*)d_ws;
  float* lksum = ws;                               // NCH_*DK_      = 32768
  float* lkv = lksum + (size_t)NCH_ * DK_;         // NCH_*DK_*DV_  = 2,097,152
  float* pksum = lkv + (size_t)NCH_ * DK_ * DV_;   // NCH_*DK_      = 32768
  float* pkv = pksum + (size_t)NCH_ * DK_;         // NCH_*DK_*DV_  = 2,097,152

  void* args[] = {(void*)&q, (void*)&k, (void*)&v, (void*)&om,
                  (void*)&lksum, (void*)&lkv, (void*)&pksum, (void*)&pkv,
                  (void*)&out};
  hipLaunchCooperativeKernel((void*)fused_kernel, dim3(NCH_), dim3(256),
                             args, 0, stream);
}